// Round 1
// baseline (9391.869 us; speedup 1.0000x reference)
//
#include <hip/hip_runtime.h>
#include <math.h>

#define HIDDEN 768
#define EPSV 1e-8f

// ---------------- latent row norms ----------------
__global__ void pcl_latnorm(const float* __restrict__ l1,
                            const float* __restrict__ l2,
                            float* __restrict__ ln) {
    int r = blockIdx.x;        // 0..2047
    int t = threadIdx.x;       // 64 threads
    const float* src = (r < 1024) ? (l1 + (size_t)r * HIDDEN)
                                  : (l2 + (size_t)(r - 1024) * HIDDEN);
    const float4* s4 = (const float4*)src;
    float s = 0.f;
#pragma unroll
    for (int i = 0; i < 3; ++i) {
        float4 v = s4[t + 64 * i];
        s += v.x * v.x + v.y * v.y + v.z * v.z + v.w * v.w;
    }
#pragma unroll
    for (int off = 32; off; off >>= 1) s += __shfl_xor(s, off, 64);
    if (t == 0) ln[r] = sqrtf(s);
}

// ---------------- fused conv + cosine + exp-sum ----------------
// grid: 1152 blocks (64 images * 18 groups of 32 patches), 512 threads
// dynamic LDS layout:
//   xlds[32][68]   @ 0        (8704 B)   X k-chunk (32 patches x 64 k)
//   wl  [128][68]  @ 8704     (34816 B)  W d-tile / latent l-tile (128 rows x 64 k)
//   ps  [32][772]  @ 43520    (98816 B)  conv output P (32 x 768)
//   pns [32]       @ 142336   (128 B)    patch norms
#define SMEM_BYTES 142464

__global__ __launch_bounds__(512, 2)
void pcl_main(const float* __restrict__ x, const float* __restrict__ w,
              const float* __restrict__ bias,
              const float* __restrict__ l1, const float* __restrict__ l2,
              const float* __restrict__ ln, double* __restrict__ partials) {
    extern __shared__ char smem[];
    float (*xlds)[68] = (float (*)[68])(smem);
    float (*wl)[68]   = (float (*)[68])(smem + 8704);
    float (*ps)[772]  = (float (*)[772])(smem + 43520);
    float* pns        = (float*)(smem + 142336);

    const int t   = threadIdx.x;
    const int blk = blockIdx.x;
    const int b   = blk / 18;          // image
    const int pbase = (blk % 18) * 32; // first patch of tile

    const int kk  = t & 63;            // k-lane for staging loads
    const int lr0 = t >> 6;            // row base for staging loads (0..7)
    const int mg  = t >> 5;            // 0..15 -> patch rows {mg, mg+16}
    const int dl  = t & 31;            // 0..31 -> cols {dl+32q}

    // precompute X row bases for the 4 staging slots (m = lr0 + 8*rep)
    int xrow[4];
#pragma unroll
    for (int rep = 0; rep < 4; ++rep) {
        int m = lr0 + 8 * rep;
        int n = pbase + m;
        int ph = n / 24, pw = n % 24;
        xrow[rep] = ((b * 3) * 384 + ph * 16) * 384 + pw * 16 + (kk & 15);
    }

    // ================= conv GEMM: P = Xpatch * W^T + bias =================
    for (int dt = 0; dt < 6; ++dt) {          // 768 d in tiles of 128
        float acc[2][4] = {};
        for (int kc = 0; kc < 12; ++kc) {     // 768 k in chunks of 64
            __syncthreads();
            // stage X chunk 32x64
            int u = kc * 4 + (kk >> 4);       // 0..47
            int xoff = (u >> 4) * 147456 + (u & 15) * 384;  // c*384*384 + i*384
#pragma unroll
            for (int rep = 0; rep < 4; ++rep)
                xlds[lr0 + 8 * rep][kk] = x[(size_t)xrow[rep] + xoff];
            // stage W tile 128x64
#pragma unroll
            for (int rep = 0; rep < 16; ++rep) {
                int d = lr0 + 8 * rep;
                wl[d][kk] = w[(size_t)(dt * 128 + d) * 768 + kc * 64 + kk];
            }
            __syncthreads();
            const float4* xa = (const float4*)xlds[mg];
            const float4* xb = (const float4*)xlds[mg + 16];
#pragma unroll
            for (int k4 = 0; k4 < 16; ++k4) {
                float4 va = xa[k4], vb = xb[k4];
#pragma unroll
                for (int q = 0; q < 4; ++q) {
                    float4 wv = ((const float4*)wl[dl + 32 * q])[k4];
                    acc[0][q] += va.x * wv.x + va.y * wv.y + va.z * wv.z + va.w * wv.w;
                    acc[1][q] += vb.x * wv.x + vb.y * wv.y + vb.z * wv.z + vb.w * wv.w;
                }
            }
        }
        __syncthreads();
#pragma unroll
        for (int q = 0; q < 4; ++q) {
            int d = dt * 128 + dl + 32 * q;
            float bv = bias[d];
            ps[mg][d]      = acc[0][q] + bv;
            ps[mg + 16][d] = acc[1][q] + bv;
        }
    }
    __syncthreads();

    // ================= patch norms =================
    {
        int m = t >> 4, d0 = t & 15;
        float s = 0.f;
#pragma unroll
        for (int q = 0; q < 48; ++q) { float v = ps[m][d0 + 16 * q]; s += v * v; }
        s += __shfl_xor(s, 1); s += __shfl_xor(s, 2);
        s += __shfl_xor(s, 4); s += __shfl_xor(s, 8);
        if (d0 == 0) pns[m] = sqrtf(s);
    }
    __syncthreads();
    const float pn0 = pns[mg], pn1 = pns[mg + 16];

    // ================= score GEMM + exp accumulation =================
    double sfar = 0.0, sclose = 0.0;
    for (int lt = 0; lt < 16; ++lt) {         // 2048 latent rows in tiles of 128
        float acc[2][4] = {};
        for (int kc = 0; kc < 12; ++kc) {
            __syncthreads();
#pragma unroll
            for (int rep = 0; rep < 16; ++rep) {
                int row = lr0 + 8 * rep;
                int lg = lt * 128 + row;
                const float* src = (lg < 1024) ? (l1 + (size_t)lg * HIDDEN)
                                               : (l2 + (size_t)(lg - 1024) * HIDDEN);
                wl[row][kk] = src[kc * 64 + kk];
            }
            __syncthreads();
            const float4* pa = (const float4*)ps[mg];
            const float4* pb = (const float4*)ps[mg + 16];
#pragma unroll
            for (int k4 = 0; k4 < 16; ++k4) {
                float4 va = pa[kc * 16 + k4], vb = pb[kc * 16 + k4];
#pragma unroll
                for (int q = 0; q < 4; ++q) {
                    float4 wv = ((const float4*)wl[dl + 32 * q])[k4];
                    acc[0][q] += va.x * wv.x + va.y * wv.y + va.z * wv.z + va.w * wv.w;
                    acc[1][q] += vb.x * wv.x + vb.y * wv.y + vb.z * wv.z + vb.w * wv.w;
                }
            }
        }
#pragma unroll
        for (int q = 0; q < 4; ++q) {
            int lg = lt * 128 + dl + 32 * q;
            float lnv = ln[lg];
            float den0 = fmaxf(pn0 * lnv, EPSV);
            float den1 = fmaxf(pn1 * lnv, EPSV);
            float e0 = __expf(2.0f * (acc[0][q] / den0));   // /TAU with TAU=0.5
            float e1 = __expf(2.0f * (acc[1][q] / den1));
            if (lg < 1024) sfar += (double)e0 + (double)e1;
            else           sclose += (double)e0 + (double)e1;
        }
    }

    // ================= block reduction =================
#pragma unroll
    for (int off = 32; off; off >>= 1) {
        sfar   += __shfl_down(sfar, off);
        sclose += __shfl_down(sclose, off);
    }
    __syncthreads();
    double* red = (double*)smem;   // overlays xlds (unused now)
    int wid = t >> 6, lane = t & 63;
    if (lane == 0) { red[wid * 2] = sfar; red[wid * 2 + 1] = sclose; }
    __syncthreads();
    if (t == 0) {
        double f = 0.0, c = 0.0;
#pragma unroll
        for (int i = 0; i < 8; ++i) { f += red[i * 2]; c += red[i * 2 + 1]; }
        partials[blk * 2]     = f;
        partials[blk * 2 + 1] = c;
    }
}

// ---------------- finish: per-batch log ratio, mean ----------------
__global__ void pcl_finish(const double* __restrict__ partials, float* __restrict__ out) {
    int b = threadIdx.x;   // 64 threads = 64 batches
    double f = 0.0, c = 0.0;
#pragma unroll
    for (int i = 0; i < 18; ++i) {
        f += partials[(b * 18 + i) * 2];
        c += partials[(b * 18 + i) * 2 + 1];
    }
    double lb = log(f) - log(c);   // -log(sum_close/sum_far)
#pragma unroll
    for (int off = 32; off; off >>= 1) lb += __shfl_down(lb, off);
    if (b == 0) out[0] = (float)(lb * (1.0 / 64.0));
}

extern "C" void kernel_launch(void* const* d_in, const int* in_sizes, int n_in,
                              void* d_out, int out_size, void* d_ws, size_t ws_size,
                              hipStream_t stream) {
    const float* x    = (const float*)d_in[0];
    const float* w    = (const float*)d_in[1];
    const float* bias = (const float*)d_in[2];
    const float* l1   = (const float*)d_in[3];
    const float* l2   = (const float*)d_in[4];
    float* out = (float*)d_out;

    float*  ln       = (float*)d_ws;                       // 2048 floats
    double* partials = (double*)((char*)d_ws + 8192);      // 1152*2 doubles

    (void)hipFuncSetAttribute((const void*)pcl_main,
                              hipFuncAttributeMaxDynamicSharedMemorySize, SMEM_BYTES);

    pcl_latnorm<<<2048, 64, 0, stream>>>(l1, l2, ln);
    pcl_main<<<1152, 512, SMEM_BYTES, stream>>>(x, w, bias, l1, l2, ln, partials);
    pcl_finish<<<1, 64, 0, stream>>>(partials, out);
}

// Round 2
// 460.879 us; speedup vs baseline: 20.3781x; 20.3781x over previous
//
#include <hip/hip_runtime.h>
#include <math.h>

using f32x4  = __attribute__((ext_vector_type(4))) float;
using bf16x8 = __attribute__((ext_vector_type(8))) short;

typedef const __attribute__((address_space(1))) void gas_void;
typedef __attribute__((address_space(3))) void las_void;

__device__ __forceinline__ void gl16(const void* g, void* l) {
    __builtin_amdgcn_global_load_lds((gas_void*)g, (las_void*)l, 16, 0, 0);
}

__device__ __forceinline__ unsigned short f2bf(float f) {
    union { float f; unsigned u; } v; v.f = f;
    unsigned r = v.u + 0x7fffu + ((v.u >> 16) & 1u);   // RNE
    return (unsigned short)(r >> 16);
}
__device__ __forceinline__ float bf2f(unsigned short u) {
    return __uint_as_float(((unsigned)u) << 16);
}

// ---------------- prep: W, latents -> bf16 in ws; latent norms ----------------
__global__ void pcl_prep(const float* __restrict__ w,
                         const float* __restrict__ l1, const float* __restrict__ l2,
                         unsigned short* __restrict__ wsW,
                         unsigned short* __restrict__ wsL,
                         float* __restrict__ ln) {
    int r = blockIdx.x, t = threadIdx.x;   // 2816 blocks x 64 threads
    if (r < 768) {
        const float* src = w + (size_t)r * 768;
        unsigned short* dst = wsW + (size_t)r * 768;
#pragma unroll
        for (int i = 0; i < 12; ++i) dst[t + 64 * i] = f2bf(src[t + 64 * i]);
    } else {
        int lr = r - 768;
        const float* src = (lr < 1024) ? l1 + (size_t)lr * 768 : l2 + (size_t)(lr - 1024) * 768;
        unsigned short* dst = wsL + (size_t)lr * 768;
        float s = 0.f;
#pragma unroll
        for (int i = 0; i < 12; ++i) {
            unsigned short u = f2bf(src[t + 64 * i]);
            dst[t + 64 * i] = u;
            float f = bf2f(u); s += f * f;
        }
#pragma unroll
        for (int off = 32; off; off >>= 1) s += __shfl_xor(s, off, 64);
        if (t == 0) ln[lr] = sqrtf(s);   // norm of bf16-rounded row (consistency)
    }
}

// ---------------- main fused kernel ----------------
// grid 576 = 64 images x 9 tiles of 64 patches; 512 threads (8 waves)
// LDS: XS [64][64]bf16 @0 (8K) | WS [384][64]bf16 @8192 (48K) |
//      PS [64][768]bf16 @57344 (96K) | PN 64 f32 @155648
// swizzle: 16B slot s at row r stored at slot s^(r&7)
#define LDS_BYTES 155904

__global__ __launch_bounds__(512, 2)
void pcl_main(const float* __restrict__ x, const unsigned short* __restrict__ wsW,
              const float* __restrict__ bias, const unsigned short* __restrict__ wsL,
              const float* __restrict__ ln, double* __restrict__ partials) {
    extern __shared__ char smem[];
    char* XS = smem;
    char* WS = smem + 8192;
    char* PS = smem + 57344;
    float* PN = (float*)(smem + 155648);

    const int t = threadIdx.x;
    const int w = t >> 6, l = t & 63;
    const int blk = blockIdx.x;
    const int b = blk / 9;
    const int pt = blk % 9;

    // X staging ids: row sr (0..63), slot ss (0..7)
    const int sr = t >> 3, ss = t & 7;
    {
    }
    const int n = pt * 64 + sr;
    const int ph = n / 24, pw = n % 24;
    const float* xbase = x + (((size_t)(b * 3)) * 384 + ph * 16) * 384 + pw * 16;
    char* xw = XS + sr * 128 + ((ss ^ (sr & 7)) << 4);

    // gload staging ids
    const int ir = l >> 3, is = l & 7, s2 = is ^ ir;

    // MFMA lane ids
    const int lm = l & 15;   // frag row/col
    const int lg4 = l >> 4;  // k-group

    // ================= GEMM1: P = Xpatch * W^T + bias =================
    for (int dt = 0; dt < 2; ++dt) {
        f32x4 acc[4][3];
#pragma unroll
        for (int m = 0; m < 4; ++m)
#pragma unroll
            for (int nn = 0; nn < 3; ++nn) acc[m][nn] = (f32x4)0.f;

        for (int kc = 0; kc < 12; ++kc) {
            __syncthreads();
            // stage X chunk [64][64] (gather fp32 -> bf16, swizzled ds_write_b128)
            {
                int c = kc >> 2, i = (kc & 3) * 4 + (ss >> 1), j0 = (ss & 1) * 8;
                const float* src = xbase + (size_t)c * 147456 + i * 384 + j0;
                f32x4 v0 = *(const f32x4*)(src);
                f32x4 v1 = *(const f32x4*)(src + 4);
                bf16x8 pkt;
#pragma unroll
                for (int j = 0; j < 4; ++j) {
                    pkt[j]     = (short)f2bf(v0[j]);
                    pkt[4 + j] = (short)f2bf(v1[j]);
                }
                *(bf16x8*)xw = pkt;
            }
            // stage W tile [384][64] via global_load_lds (source carries inverse swizzle)
#pragma unroll
            for (int rep = 0; rep < 6; ++rep) {
                int c2 = w + 8 * rep;          // 1KB chunk id, 0..47
                int r = c2 * 8 + ir;           // row 0..383
                const unsigned short* src = wsW + ((size_t)(dt * 384 + r)) * 768 + kc * 64 + s2 * 8;
                gl16(src, WS + c2 * 1024);
            }
            __syncthreads();
            // compute: wave w owns cols [w*48, w*48+48)
#pragma unroll
            for (int ks = 0; ks < 2; ++ks) {
                int slot = ks * 4 + lg4;
                bf16x8 a[4], bb[3];
#pragma unroll
                for (int m = 0; m < 4; ++m) {
                    int r = m * 16 + lm;
                    a[m] = *(const bf16x8*)(XS + r * 128 + ((slot ^ (r & 7)) << 4));
                }
#pragma unroll
                for (int nn = 0; nn < 3; ++nn) {
                    int r = w * 48 + nn * 16 + lm;
                    bb[nn] = *(const bf16x8*)(WS + r * 128 + ((slot ^ (r & 7)) << 4));
                }
#pragma unroll
                for (int m = 0; m < 4; ++m)
#pragma unroll
                    for (int nn = 0; nn < 3; ++nn)
                        acc[m][nn] = __builtin_amdgcn_mfma_f32_16x16x32_bf16(a[m], bb[nn], acc[m][nn], 0, 0, 0);
            }
        }
        // write P tile (bias added, bf16, swizzled)
#pragma unroll
        for (int nn = 0; nn < 3; ++nn) {
            int d = dt * 384 + w * 48 + nn * 16 + lm;
            float bv = bias[d];
            int sd = d >> 3, dlow = d & 7;
#pragma unroll
            for (int m = 0; m < 4; ++m)
#pragma unroll
                for (int j = 0; j < 4; ++j) {
                    int r = m * 16 + lg4 * 4 + j;
                    *(unsigned short*)(PS + r * 1536 + ((sd ^ (r & 7)) << 4) + dlow * 2) =
                        f2bf(acc[m][nn][j] + bv);
                }
        }
    }
    __syncthreads();

    // ================= patch norms (from bf16 P) =================
    {
        float s = 0.f;
#pragma unroll
        for (int qq = 0; qq < 12; ++qq) {
            int sd = ss + 8 * qq;
            bf16x8 v = *(const bf16x8*)(PS + sr * 1536 + ((sd ^ (sr & 7)) << 4));
#pragma unroll
            for (int j = 0; j < 8; ++j) {
                float f = bf2f((unsigned short)v[j]);
                s += f * f;
            }
        }
        s += __shfl_xor(s, 1); s += __shfl_xor(s, 2); s += __shfl_xor(s, 4);
        if (ss == 0) PN[sr] = sqrtf(s);
    }
    __syncthreads();

    // ================= GEMM2: scores + exp-sum =================
    double sfar = 0.0, sclose = 0.0;
    for (int lt = 0; lt < 8; ++lt) {
        f32x4 acc[4][2];
#pragma unroll
        for (int m = 0; m < 4; ++m) { acc[m][0] = (f32x4)0.f; acc[m][1] = (f32x4)0.f; }

        for (int kc = 0; kc < 12; ++kc) {
            __syncthreads();
            // stage latent tile [256][64]
#pragma unroll
            for (int rep = 0; rep < 4; ++rep) {
                int c2 = w + 8 * rep;          // 0..31
                int r = c2 * 8 + ir;           // 0..255
                const unsigned short* src = wsL + ((size_t)(lt * 256 + r)) * 768 + kc * 64 + s2 * 8;
                gl16(src, WS + c2 * 1024);
            }
            __syncthreads();
#pragma unroll
            for (int ks = 0; ks < 2; ++ks) {
                int slotA = kc * 8 + ks * 4 + lg4;
                int slotB = ks * 4 + lg4;
                bf16x8 a[4], bb[2];
#pragma unroll
                for (int m = 0; m < 4; ++m) {
                    int r = m * 16 + lm;
                    a[m] = *(const bf16x8*)(PS + r * 1536 + (((slotA ^ (r & 7))) << 4));
                }
#pragma unroll
                for (int nn = 0; nn < 2; ++nn) {
                    int r = w * 32 + nn * 16 + lm;
                    bb[nn] = *(const bf16x8*)(WS + r * 128 + ((slotB ^ (r & 7)) << 4));
                }
#pragma unroll
                for (int m = 0; m < 4; ++m)
#pragma unroll
                    for (int nn = 0; nn < 2; ++nn)
                        acc[m][nn] = __builtin_amdgcn_mfma_f32_16x16x32_bf16(a[m], bb[nn], acc[m][nn], 0, 0, 0);
            }
        }
        // epilogue: cos -> exp(2*cos) -> fp64 accumulate
#pragma unroll
        for (int nn = 0; nn < 2; ++nn) {
            int lg = lt * 256 + w * 32 + nn * 16 + lm;
            float lnv = ln[lg];
            double acc_loc = 0.0;
#pragma unroll
            for (int m = 0; m < 4; ++m)
#pragma unroll
                for (int j = 0; j < 4; ++j) {
                    int r = m * 16 + lg4 * 4 + j;
                    float pn = PN[r];
                    float den = fmaxf(pn * lnv, 1e-8f);
                    acc_loc += (double)__expf(2.0f * (acc[m][nn][j] / den));
                }
            if (lg < 1024) sfar += acc_loc; else sclose += acc_loc;
        }
    }

    // ================= block reduction =================
#pragma unroll
    for (int off = 32; off; off >>= 1) {
        sfar   += __shfl_down(sfar, off);
        sclose += __shfl_down(sclose, off);
    }
    __syncthreads();
    double* red = (double*)XS;
    if (l == 0) { red[w * 2] = sfar; red[w * 2 + 1] = sclose; }
    __syncthreads();
    if (t == 0) {
        double f = 0.0, c = 0.0;
#pragma unroll
        for (int i = 0; i < 8; ++i) { f += red[i * 2]; c += red[i * 2 + 1]; }
        partials[blk * 2]     = f;
        partials[blk * 2 + 1] = c;
    }
}

// ---------------- finish ----------------
__global__ void pcl_finish(const double* __restrict__ partials, float* __restrict__ out) {
    int b = threadIdx.x;   // 64 batches
    double f = 0.0, c = 0.0;
#pragma unroll
    for (int i = 0; i < 9; ++i) {
        f += partials[(b * 9 + i) * 2];
        c += partials[(b * 9 + i) * 2 + 1];
    }
    double lb = log(f) - log(c);
#pragma unroll
    for (int off = 32; off; off >>= 1) lb += __shfl_down(lb, off);
    if (b == 0) out[0] = (float)(lb * (1.0 / 64.0));
}

extern "C" void kernel_launch(void* const* d_in, const int* in_sizes, int n_in,
                              void* d_out, int out_size, void* d_ws, size_t ws_size,
                              hipStream_t stream) {
    const float* x    = (const float*)d_in[0];
    const float* w    = (const float*)d_in[1];
    const float* bias = (const float*)d_in[2];
    const float* l1   = (const float*)d_in[3];
    const float* l2   = (const float*)d_in[4];
    float* out = (float*)d_out;

    unsigned short* wsW = (unsigned short*)d_ws;                       // 768*768 bf16
    unsigned short* wsL = (unsigned short*)((char*)d_ws + 1179648);    // 2048*768 bf16
    float* ln           = (float*)((char*)d_ws + 4325376);             // 2048 f32
    double* partials    = (double*)((char*)d_ws + 4333568);            // 576*2 f64

    (void)hipFuncSetAttribute((const void*)pcl_main,
                              hipFuncAttributeMaxDynamicSharedMemorySize, LDS_BYTES);

    pcl_prep<<<2816, 64, 0, stream>>>(w, l1, l2, wsW, wsL, ln);
    pcl_main<<<576, 512, LDS_BYTES, stream>>>(x, wsW, bias, wsL, ln, partials);
    pcl_finish<<<1, 64, 0, stream>>>(partials, out);
}

// Round 3
// 382.632 us; speedup vs baseline: 24.5454x; 1.2045x over previous
//
#include <hip/hip_runtime.h>
#include <math.h>

using f32x4  = __attribute__((ext_vector_type(4))) float;
using bf16x8 = __attribute__((ext_vector_type(8))) short;

typedef const __attribute__((address_space(1))) void gas_void;
typedef __attribute__((address_space(3))) void las_void;

__device__ __forceinline__ void gl16(const void* g, void* l) {
    __builtin_amdgcn_global_load_lds((gas_void*)g, (las_void*)l, 16, 0, 0);
}

__device__ __forceinline__ unsigned short f2bf(float f) {
    union { float f; unsigned u; } v; v.f = f;
    unsigned r = v.u + 0x7fffu + ((v.u >> 16) & 1u);   // RNE
    return (unsigned short)(r >> 16);
}
__device__ __forceinline__ float bf2f(unsigned short u) {
    return __uint_as_float(((unsigned)u) << 16);
}

// ---------------- prep: X (NCHW fp32) -> patch-major bf16 Xp[36864][768] ----------------
__global__ void pcl_prep_x(const float* __restrict__ x, unsigned short* __restrict__ xp) {
    int t = threadIdx.x;              // 256
    int wv = t >> 6, l = t & 63;
    int p = blockIdx.x * 4 + wv;      // patch id
    int b = p / 576, n = p % 576;
    int ph = n / 24, pw = n % 24;
    const float* base = x + ((size_t)(b * 3)) * 147456 + (ph * 16) * 384 + pw * 16;
    unsigned* dst = (unsigned*)(xp + (size_t)p * 768);
#pragma unroll
    for (int q = 0; q < 6; ++q) {
        int k = q * 128 + l * 2;
        int c = k >> 8, i = (k >> 4) & 15, j = k & 15;
        const float* s = base + (size_t)c * 147456 + i * 384 + j;
        float2 v = *(const float2*)s;
        unsigned lo = f2bf(v.x), hi = f2bf(v.y);
        dst[q * 64 + l] = lo | (hi << 16);
    }
}

// ---------------- prep: W -> bf16; latents -> row-normalized bf16 ----------------
__global__ void pcl_prep_wl(const float* __restrict__ w,
                            const float* __restrict__ l1, const float* __restrict__ l2,
                            unsigned short* __restrict__ wsW,
                            unsigned short* __restrict__ wsL) {
    int r = blockIdx.x, t = threadIdx.x;   // 2816 x 64
    if (r < 768) {
        const float* src = w + (size_t)r * 768;
        unsigned short* dst = wsW + (size_t)r * 768;
#pragma unroll
        for (int i = 0; i < 12; ++i) dst[t + 64 * i] = f2bf(src[t + 64 * i]);
    } else {
        int lr = r - 768;
        const float* src = (lr < 1024) ? l1 + (size_t)lr * 768 : l2 + (size_t)(lr - 1024) * 768;
        unsigned short* dst = wsL + (size_t)lr * 768;
        float vals[12];
        float s = 0.f;
#pragma unroll
        for (int i = 0; i < 12; ++i) {
            float f = bf2f(f2bf(src[t + 64 * i]));
            vals[i] = f; s += f * f;
        }
#pragma unroll
        for (int off = 32; off; off >>= 1) s += __shfl_xor(s, off, 64);
        float rn = 1.0f / sqrtf(s);
#pragma unroll
        for (int i = 0; i < 12; ++i) dst[t + 64 * i] = f2bf(vals[i] * rn);
    }
}

// ---------------- main fused kernel ----------------
// grid 576 = 64 images x 9 tiles of 64 patches; 512 threads (8 waves)
// LDS: H0 32KB @0 | H1 32KB @32768 | PS [64][768]bf16 swizzled @65536 (96KB) = 160KiB
// GEMM1 inside each H half: W-tile [128][64] @0 (16KB), X-tile [64][64] @16384 (8KB)
// swizzle: 16B slot s at row r stored at slot s^(r&7) (both sides)
#define LDS_BYTES 163840

__global__ __launch_bounds__(512, 1)
void pcl_main(const unsigned short* __restrict__ xp,
              const unsigned short* __restrict__ wsW,
              const float* __restrict__ bias,
              const unsigned short* __restrict__ wsL,
              double* __restrict__ partials) {
    extern __shared__ char smem[];
    char* H0 = smem;
    char* H1 = smem + 32768;
    char* PS = smem + 65536;

    const int t = threadIdx.x;
    const int w = t >> 6, l = t & 63;
    const int blk = blockIdx.x;
    const int b = blk / 9, pt = blk % 9;
    const int pbase = b * 576 + pt * 64;

    const int ir = l >> 3;             // staging row-in-chunk
    const int s2 = (l & 7) ^ ir;       // inverse-swizzled source slot
    const int lm = l & 15, lg4 = l >> 4;

    // ---- staging helpers (dest = wave-uniform base; HW adds lane*16) ----
    auto stageW = [&](int dt, int kc, char* H) {
#pragma unroll
        for (int rep = 0; rep < 2; ++rep) {
            int c2 = w * 2 + rep;              // 0..15
            int row = c2 * 8 + ir;             // 0..127
            gl16(wsW + (size_t)(dt * 128 + row) * 768 + kc * 64 + s2 * 8, H + c2 * 1024);
        }
    };
    auto stageX = [&](int kc, char* H) {
        int row = w * 8 + ir;                  // 0..63
        gl16(xp + (size_t)(pbase + row) * 768 + kc * 64 + s2 * 8, H + 16384 + w * 1024);
    };
    auto stageL = [&](int lt, int kc, char* H) {
#pragma unroll
        for (int rep = 0; rep < 4; ++rep) {
            int c2 = w * 4 + rep;              // 0..31
            int row = c2 * 8 + ir;             // 0..255
            gl16(wsL + (size_t)(lt * 256 + row) * 768 + kc * 64 + s2 * 8, H + c2 * 1024);
        }
    };

    // ================= GEMM1: P = Xpatch * W^T (kc outer, dt inner, 2-phase) ==========
    f32x4 acc[6][4];
#pragma unroll
    for (int dt = 0; dt < 6; ++dt)
#pragma unroll
        for (int m = 0; m < 4; ++m) acc[dt][m] = (f32x4)0.f;

    stageX(0, H0);
    stageW(0, 0, H0);
    __syncthreads();

    for (int kc = 0; kc < 12; ++kc) {
        const char* HX = ((kc & 1) ? H1 : H0) + 16384;
        bf16x8 a[2][4];
#pragma unroll
        for (int ks = 0; ks < 2; ++ks)
#pragma unroll
            for (int m = 0; m < 4; ++m) {
                int r = m * 16 + lm, slot = ks * 4 + lg4;
                a[ks][m] = *(const bf16x8*)(HX + r * 128 + ((slot ^ (r & 7)) << 4));
            }
#pragma unroll
        for (int dt = 0; dt < 6; ++dt) {
            int cur = (kc * 6 + dt) & 1;
            char* Hc = cur ? H1 : H0;
            char* Hn = cur ? H0 : H1;
            // prefetch next step
            if (dt < 5) {
                stageW(dt + 1, kc, Hn);
            } else if (kc < 11) {
                stageW(0, kc + 1, Hn);
                stageX(kc + 1, (kc & 1) ? H0 : H1);   // half (kc+1)&1
            }
            // compute current
#pragma unroll
            for (int ks = 0; ks < 2; ++ks) {
                int slot = ks * 4 + lg4;
                int r = w * 16 + lm;
                bf16x8 bb = *(const bf16x8*)(Hc + r * 128 + ((slot ^ (r & 7)) << 4));
#pragma unroll
                for (int m = 0; m < 4; ++m)
                    acc[dt][m] = __builtin_amdgcn_mfma_f32_16x16x32_bf16(a[ks][m], bb, acc[dt][m], 0, 0, 0);
            }
            __syncthreads();
        }
    }

    // ---- epilogue: bias add, write PS bf16 (swizzled) ----
#pragma unroll
    for (int dt = 0; dt < 6; ++dt) {
        int d = dt * 128 + w * 16 + lm;
        float bv = bias[d];
        int sd = d >> 3, dlow = d & 7;
#pragma unroll
        for (int m = 0; m < 4; ++m)
#pragma unroll
            for (int j = 0; j < 4; ++j) {
                int r = m * 16 + lg4 * 4 + j;
                *(unsigned short*)(PS + r * 1536 + ((sd ^ (r & 7)) << 4) + dlow * 2) =
                    f2bf(acc[dt][m][j] + bv);
            }
    }
    __syncthreads();

    // ---- patch norms + in-place row normalization of PS ----
    {
        int srow = (t >> 3) & 63, ss = t & 7;
        float s = 0.f;
        bf16x8 v[12];
#pragma unroll
        for (int q = 0; q < 12; ++q) {
            int sd = ss + 8 * q;
            v[q] = *(const bf16x8*)(PS + srow * 1536 + ((sd ^ (srow & 7)) << 4));
#pragma unroll
            for (int j = 0; j < 8; ++j) { float f = bf2f((unsigned short)v[q][j]); s += f * f; }
        }
        s += __shfl_xor(s, 1); s += __shfl_xor(s, 2); s += __shfl_xor(s, 4);
        float rn = 1.0f / sqrtf(s);
#pragma unroll
        for (int q = 0; q < 12; ++q) {
            int sd = ss + 8 * q;
            bf16x8 o;
#pragma unroll
            for (int j = 0; j < 8; ++j) o[j] = (short)f2bf(bf2f((unsigned short)v[q][j]) * rn);
            *(bf16x8*)(PS + srow * 1536 + ((sd ^ (srow & 7)) << 4)) = o;
        }
    }
    __syncthreads();

    // ================= GEMM2: scores + exp-sum (lt outer, kc inner, 2-phase) ==========
    double sfar = 0.0, sclose = 0.0;
    stageL(0, 0, H0);
    __syncthreads();

    for (int lt = 0; lt < 8; ++lt) {
        f32x4 acc2[4][2];
#pragma unroll
        for (int m = 0; m < 4; ++m) { acc2[m][0] = (f32x4)0.f; acc2[m][1] = (f32x4)0.f; }

        for (int kc = 0; kc < 12; ++kc) {
            int st = lt * 12 + kc;
            char* Hc = (st & 1) ? H1 : H0;
            char* Hn = (st & 1) ? H0 : H1;
            // prefetch next step
            if (kc < 11)      stageL(lt, kc + 1, Hn);
            else if (lt < 7)  stageL(lt + 1, 0, Hn);
            // compute current
#pragma unroll
            for (int ks = 0; ks < 2; ++ks) {
                int slotB = ks * 4 + lg4;
                int slotA = kc * 8 + slotB;
                bf16x8 a[4], bb[2];
#pragma unroll
                for (int m = 0; m < 4; ++m) {
                    int r = m * 16 + lm;
                    a[m] = *(const bf16x8*)(PS + r * 1536 + ((slotA ^ (r & 7)) << 4));
                }
#pragma unroll
                for (int nn = 0; nn < 2; ++nn) {
                    int r = w * 32 + nn * 16 + lm;
                    bb[nn] = *(const bf16x8*)(Hc + r * 128 + ((slotB ^ (r & 7)) << 4));
                }
#pragma unroll
                for (int m = 0; m < 4; ++m)
#pragma unroll
                    for (int nn = 0; nn < 2; ++nn)
                        acc2[m][nn] = __builtin_amdgcn_mfma_f32_16x16x32_bf16(a[m], bb[nn], acc2[m][nn], 0, 0, 0);
            }
            __syncthreads();
        }
        // epilogue: exp(2*cos), f32 within-lt, f64 across
#pragma unroll
        for (int nn = 0; nn < 2; ++nn) {
            int lg = lt * 256 + w * 32 + nn * 16 + lm;
            float es = 0.f;
#pragma unroll
            for (int m = 0; m < 4; ++m)
#pragma unroll
                for (int j = 0; j < 4; ++j) es += __expf(2.0f * acc2[m][nn][j]);
            if (lg < 1024) sfar += (double)es; else sclose += (double)es;
        }
    }

    // ================= block reduction =================
#pragma unroll
    for (int off = 32; off; off >>= 1) {
        sfar   += __shfl_down(sfar, off);
        sclose += __shfl_down(sclose, off);
    }
    double* red = (double*)H0;
    if (l == 0) { red[w * 2] = sfar; red[w * 2 + 1] = sclose; }
    __syncthreads();
    if (t == 0) {
        double f = 0.0, c = 0.0;
#pragma unroll
        for (int i = 0; i < 8; ++i) { f += red[i * 2]; c += red[i * 2 + 1]; }
        partials[blk * 2]     = f;
        partials[blk * 2 + 1] = c;
    }
}

// ---------------- finish ----------------
__global__ void pcl_finish(const double* __restrict__ partials, float* __restrict__ out) {
    int b = threadIdx.x;   // 64 batches
    double f = 0.0, c = 0.0;
#pragma unroll
    for (int i = 0; i < 9; ++i) {
        f += partials[(b * 9 + i) * 2];
        c += partials[(b * 9 + i) * 2 + 1];
    }
    double lb = log(f) - log(c);
#pragma unroll
    for (int off = 32; off; off >>= 1) lb += __shfl_down(lb, off);
    if (b == 0) out[0] = (float)(lb * (1.0 / 64.0));
}

extern "C" void kernel_launch(void* const* d_in, const int* in_sizes, int n_in,
                              void* d_out, int out_size, void* d_ws, size_t ws_size,
                              hipStream_t stream) {
    const float* x    = (const float*)d_in[0];
    const float* w    = (const float*)d_in[1];
    const float* bias = (const float*)d_in[2];
    const float* l1   = (const float*)d_in[3];
    const float* l2   = (const float*)d_in[4];
    float* out = (float*)d_out;

    unsigned short* xp  = (unsigned short*)d_ws;                        // 36864*768 bf16
    unsigned short* wsW = (unsigned short*)((char*)d_ws + 56623104);    // 768*768 bf16
    unsigned short* wsL = (unsigned short*)((char*)d_ws + 57802752);    // 2048*768 bf16
    double* partials    = (double*)((char*)d_ws + 60948480);            // 576*2 f64

    (void)hipFuncSetAttribute((const void*)pcl_main,
                              hipFuncAttributeMaxDynamicSharedMemorySize, LDS_BYTES);

    pcl_prep_x<<<9216, 256, 0, stream>>>(x, xp);
    pcl_prep_wl<<<2816, 64, 0, stream>>>(w, l1, l2, wsW, wsL);
    pcl_main<<<576, 512, LDS_BYTES, stream>>>(xp, wsW, bias, wsL, partials);
    pcl_finish<<<1, 64, 0, stream>>>(partials, out);
}